// Round 1
// baseline (238.544 us; speedup 1.0000x reference)
//
#include <hip/hip_runtime.h>
#include <cstdint>
#include <cstddef>

// ---------------------------------------------------------------------------
// ReLA block: y = LN2( (causal_relu( (LN1(x)Wq*s) (LN1(x)Wk)^T ) (LN1(x)Wv)) Wout )
// x: [2,2048,1024] fp32. HEADS=16, DIM_HEAD=64, DIM=1024. Output fp32.
// Strategy: bf16 MFMA (16x16x32) for all matmuls, fp32 accumulate.
// ---------------------------------------------------------------------------

typedef __bf16 bf16_t;
typedef __bf16 bf16x8 __attribute__((ext_vector_type(8)));
typedef __bf16 bf16x4 __attribute__((ext_vector_type(4)));
typedef float  f32x4  __attribute__((ext_vector_type(4)));

#define DEV_INLINE __device__ __forceinline__

// async global->LDS, 16B per lane. LDS dest is wave-uniform base + lane*16.
DEV_INLINE void async_copy16(void* lds, const void* g) {
  __builtin_amdgcn_global_load_lds(
      (__attribute__((address_space(1))) void*)(g),
      (__attribute__((address_space(3))) void*)(lds), 16, 0, 0);
}

// ---------------------------------------------------------------------------
// LN1: x fp32 [4096,1024] -> xn bf16 [4096,1024]
// ---------------------------------------------------------------------------
__global__ __launch_bounds__(256) void ln1_kernel(
    const float* __restrict__ x, const float* __restrict__ g,
    const float* __restrict__ bta, bf16_t* __restrict__ xn) {
  const int row = blockIdx.x;
  const int t = threadIdx.x, w = t >> 6, l = t & 63;
  const float* xr = x + (size_t)row * 1024;
  float4 v = *(const float4*)(xr + t * 4);
  float s  = v.x + v.y + v.z + v.w;
  float s2 = v.x * v.x + v.y * v.y + v.z * v.z + v.w * v.w;
  #pragma unroll
  for (int off = 32; off >= 1; off >>= 1) {
    s  += __shfl_down(s, off);
    s2 += __shfl_down(s2, off);
  }
  __shared__ float red[8];
  if (l == 0) { red[w] = s; red[4 + w] = s2; }
  __syncthreads();
  s  = red[0] + red[1] + red[2] + red[3];
  s2 = red[4] + red[5] + red[6] + red[7];
  float mu  = s * (1.0f / 1024.0f);
  float var = s2 * (1.0f / 1024.0f) - mu * mu;
  float rs  = rsqrtf(var + 1e-5f);
  float4 gv = *(const float4*)(g + t * 4);
  float4 bv = *(const float4*)(bta + t * 4);
  bf16x4 o;
  o[0] = (bf16_t)((v.x - mu) * rs * gv.x + bv.x);
  o[1] = (bf16_t)((v.y - mu) * rs * gv.y + bv.y);
  o[2] = (bf16_t)((v.z - mu) * rs * gv.z + bv.z);
  o[3] = (bf16_t)((v.w - mu) * rs * gv.w + bv.w);
  *(bf16x4*)(xn + (size_t)row * 1024 + t * 4) = o;
}

// ---------------------------------------------------------------------------
// LN2: z fp32 [4096,1024] -> out fp32 [4096,1024]
// ---------------------------------------------------------------------------
__global__ __launch_bounds__(256) void ln2_kernel(
    const float* __restrict__ z, const float* __restrict__ g,
    const float* __restrict__ bta, float* __restrict__ out) {
  const int row = blockIdx.x;
  const int t = threadIdx.x, w = t >> 6, l = t & 63;
  const float* zr = z + (size_t)row * 1024;
  float4 v = *(const float4*)(zr + t * 4);
  float s  = v.x + v.y + v.z + v.w;
  float s2 = v.x * v.x + v.y * v.y + v.z * v.z + v.w * v.w;
  #pragma unroll
  for (int off = 32; off >= 1; off >>= 1) {
    s  += __shfl_down(s, off);
    s2 += __shfl_down(s2, off);
  }
  __shared__ float red[8];
  if (l == 0) { red[w] = s; red[4 + w] = s2; }
  __syncthreads();
  s  = red[0] + red[1] + red[2] + red[3];
  s2 = red[4] + red[5] + red[6] + red[7];
  float mu  = s * (1.0f / 1024.0f);
  float var = s2 * (1.0f / 1024.0f) - mu * mu;
  float rs  = rsqrtf(var + 1e-5f);
  float4 gv = *(const float4*)(g + t * 4);
  float4 bv = *(const float4*)(bta + t * 4);
  float4 o;
  o.x = (v.x - mu) * rs * gv.x + bv.x;
  o.y = (v.y - mu) * rs * gv.y + bv.y;
  o.z = (v.z - mu) * rs * gv.z + bv.z;
  o.w = (v.w - mu) * rs * gv.w + bv.w;
  *(float4*)(out + (size_t)row * 1024 + t * 4) = o;
}

// ---------------------------------------------------------------------------
// Weight transpose+convert: w fp32 [1024][N] -> wT bf16 [N][1024]
// 64x64 tiles through LDS.
// ---------------------------------------------------------------------------
__global__ __launch_bounds__(256) void wtrans_kernel(
    const float* __restrict__ wsrc, bf16_t* __restrict__ wdstT, int N) {
  __shared__ __align__(16) float tl[64][68];  // stride 68: 16B-aligned rows, broken bank stride
  const int n0 = blockIdx.x * 64, k0 = blockIdx.y * 64;
  const int t = threadIdx.x;
  #pragma unroll
  for (int c = 0; c < 4; ++c) {
    int idx = c * 256 + t;
    int r = idx >> 4, c4 = (idx & 15) * 4;
    *(float4*)&tl[r][c4] = *(const float4*)(wsrc + (size_t)(k0 + r) * N + n0 + c4);
  }
  __syncthreads();
  #pragma unroll
  for (int c = 0; c < 2; ++c) {
    int idx = c * 256 + t;
    int nl = idx >> 3, kc = (idx & 7) * 8;
    bf16x8 o;
    #pragma unroll
    for (int ii = 0; ii < 8; ++ii) o[ii] = (bf16_t)tl[kc + ii][nl];
    *(bf16x8*)(wdstT + (size_t)(n0 + nl) * 1024 + k0 + kc) = o;
  }
}

// ---------------------------------------------------------------------------
// V transpose: v bf16 [b,h,n,64] -> vT bf16 [b,h,64,n]   (n=2048)
// ---------------------------------------------------------------------------
__global__ __launch_bounds__(256) void vtrans_kernel(
    const bf16_t* __restrict__ v, bf16_t* __restrict__ vT) {
  __shared__ __align__(16) bf16_t tl[64][72];  // stride 72 elems = 144B (16B-aligned)
  const int n0 = blockIdx.x * 64;
  const size_t bh = blockIdx.y;
  const int t = threadIdx.x;
  #pragma unroll
  for (int c = 0; c < 2; ++c) {
    int idx = c * 256 + t;
    int r = idx >> 3, c8 = (idx & 7) * 8;
    *(bf16x8*)&tl[r][c8] = *(const bf16x8*)(v + (bh * 2048 + n0 + r) * 64 + c8);
  }
  __syncthreads();
  #pragma unroll
  for (int c = 0; c < 2; ++c) {
    int idx = c * 256 + t;
    int d = idx >> 3, nc = (idx & 7) * 8;
    bf16x8 o;
    #pragma unroll
    for (int ii = 0; ii < 8; ++ii) o[ii] = tl[nc + ii][d];
    *(bf16x8*)(vT + (bh * 64 + d) * 2048 + n0 + nc) = o;
  }
}

// ---------------------------------------------------------------------------
// GEMM: C[M,N] = A[M,1024] @ Bt[N,1024]^T, bf16 in, fp32 acc.
// 128x128 tile, BK=32, 256 threads (4 waves, 2x2 of 64x64 quadrants).
// EPI=0: plain fp32 store to C0 (ldc=1024).
// EPI=1: qkv split epilogue -> q(*0.125)/k/v bf16 [b,h,2048,64].
// ---------------------------------------------------------------------------
template <int EPI>
__global__ __launch_bounds__(256, 2) void gemm128_kernel(
    const bf16_t* __restrict__ A, const bf16_t* __restrict__ Bt,
    void* __restrict__ C0, void* __restrict__ C1, void* __restrict__ C2) {
  __shared__ __align__(16) bf16_t As[128 * 32];
  __shared__ __align__(16) bf16_t Bs[128 * 32];
  const int t = threadIdx.x;
  const int w = t >> 6, l = t & 63, l15 = l & 15, quad = l >> 4;
  const int wy = w >> 1, wx = w & 1;
  const int m0 = blockIdx.y * 128, n0 = blockIdx.x * 128;

  // staging geometry: 8 chunks of 1KB per tile; chunk = w*2+c
  int arow[2], acol[2];
  #pragma unroll
  for (int c = 0; c < 2; ++c) {
    int e = (w * 2 + c) * 512 + l * 8;
    arow[c] = e >> 5;
    acol[c] = e & 31;
  }

  f32x4 acc[4][4];
  #pragma unroll
  for (int i = 0; i < 4; ++i)
    #pragma unroll
    for (int j = 0; j < 4; ++j) acc[i][j] = (f32x4)0.0f;

  for (int kt = 0; kt < 32; ++kt) {
    __syncthreads();  // prior iteration's LDS reads complete
    #pragma unroll
    for (int c = 0; c < 2; ++c) {
      async_copy16(&As[(w * 2 + c) * 512],
                   A + (size_t)(m0 + arow[c]) * 1024 + kt * 32 + acol[c]);
      async_copy16(&Bs[(w * 2 + c) * 512],
                   Bt + (size_t)(n0 + arow[c]) * 1024 + kt * 32 + acol[c]);
    }
    __syncthreads();  // staging complete (vmcnt drained by barrier)
    bf16x8 af[4], bfr[4];
    #pragma unroll
    for (int i = 0; i < 4; ++i)
      af[i] = *(const bf16x8*)&As[(wy * 64 + i * 16 + l15) * 32 + quad * 8];
    #pragma unroll
    for (int j = 0; j < 4; ++j)
      bfr[j] = *(const bf16x8*)&Bs[(wx * 64 + j * 16 + l15) * 32 + quad * 8];
    #pragma unroll
    for (int i = 0; i < 4; ++i)
      #pragma unroll
      for (int j = 0; j < 4; ++j)
        acc[i][j] = __builtin_amdgcn_mfma_f32_16x16x32_bf16(af[i], bfr[j], acc[i][j], 0, 0, 0);
  }

  // Epilogue. C/D layout: col = lane&15, row = quad*4 + reg (verified m89/m91).
  if (EPI == 0) {
    float* C = (float*)C0;
    #pragma unroll
    for (int i = 0; i < 4; ++i)
      #pragma unroll
      for (int j = 0; j < 4; ++j)
        #pragma unroll
        for (int r = 0; r < 4; ++r) {
          int m = m0 + wy * 64 + i * 16 + quad * 4 + r;
          int n = n0 + wx * 64 + j * 16 + l15;
          C[(size_t)m * 1024 + n] = acc[i][j][r];
        }
  } else {
    // this wave's 64-col quadrant lies in exactly one (which, head)
    int nb = n0 + wx * 64;
    int which = nb >> 10;             // 0=q, 1=k, 2=v
    int head = (nb & 1023) >> 6;
    bf16_t* dst = which == 0 ? (bf16_t*)C0 : which == 1 ? (bf16_t*)C1 : (bf16_t*)C2;
    float sc = which == 0 ? 0.125f : 1.0f;  // q * DIM_HEAD^-0.5
    #pragma unroll
    for (int i = 0; i < 4; ++i)
      #pragma unroll
      for (int j = 0; j < 4; ++j)
        #pragma unroll
        for (int r = 0; r < 4; ++r) {
          int m = m0 + wy * 64 + i * 16 + quad * 4 + r;
          int bq = m >> 11, pos = m & 2047;
          int d = j * 16 + l15;
          dst[(((size_t)(bq * 16 + head)) * 2048 + pos) * 64 + d] =
              (bf16_t)(acc[i][j][r] * sc);
        }
  }
}

// ---------------------------------------------------------------------------
// Causal ReLU attention (no softmax): O[i,:] = sum_{j<=i} relu(q_i . k_j) v_j
// One block per (b, h, 128-row q tile). Key tiles of 64. 4 waves; wave w owns
// query rows [w*32, w*32+32) in both the S and O matmuls.
// q,k: [b,h,2048,64] bf16 (q pre-scaled). vT: [b,h,64,2048] bf16.
// out: [b,2048,1024] bf16 (col = h*64+d).
// ---------------------------------------------------------------------------
__global__ __launch_bounds__(256) void attn_kernel(
    const bf16_t* __restrict__ q, const bf16_t* __restrict__ k,
    const bf16_t* __restrict__ vT, bf16_t* __restrict__ out) {
  __shared__ __align__(16) bf16_t Qs[128 * 64];   // 16 KB
  __shared__ __align__(16) bf16_t Ks[64 * 64];    //  8 KB
  __shared__ __align__(16) bf16_t Vts[64 * 64];   //  8 KB  (Vts[d][j])
  __shared__ __align__(16) bf16_t Ss[128 * 72];   // 18 KB  (stride 72: 16B-aligned, conflict-poor)

  const int qt = blockIdx.x, h = blockIdx.y, b = blockIdx.z;
  const int t = threadIdx.x;
  const int w = t >> 6, l = t & 63, l15 = l & 15, quad = l >> 4;
  const size_t bh = (size_t)(b * 16 + h);

  // stage Q tile once: 16 chunks (w*4+c)
  #pragma unroll
  for (int c = 0; c < 4; ++c) {
    int idx = w * 4 + c;
    int e = idx * 512 + l * 8;
    int row = e >> 6, col = e & 63;
    async_copy16(&Qs[idx * 512],
                 q + (bh * 2048 + qt * 128 + row) * 64 + col);
  }

  f32x4 acc_o[2][4];
  #pragma unroll
  for (int ti = 0; ti < 2; ++ti)
    #pragma unroll
    for (int tj = 0; tj < 4; ++tj) acc_o[ti][tj] = (f32x4)0.0f;

  const int nkt = 2 * qt + 2;
  for (int kt2 = 0; kt2 < nkt; ++kt2) {
    __syncthreads();  // prev O-matmul done with Ks/Vts/Ss; also drains Q stage on iter 0
    #pragma unroll
    for (int c = 0; c < 2; ++c) {
      int idx = w * 2 + c;
      int e = idx * 512 + l * 8;
      int row = e >> 6, col = e & 63;
      async_copy16(&Ks[idx * 512],
                   k + (bh * 2048 + kt2 * 64 + row) * 64 + col);
      async_copy16(&Vts[idx * 512],
                   vT + (bh * 64 + row) * 2048 + kt2 * 64 + col);
    }
    __syncthreads();  // K/V staged

    // S = Q . K^T : wave w -> rows [w*32, w*32+32), cols [0,64)
    f32x4 sacc[2][4];
    #pragma unroll
    for (int ti = 0; ti < 2; ++ti)
      #pragma unroll
      for (int tj = 0; tj < 4; ++tj) sacc[ti][tj] = (f32x4)0.0f;
    #pragma unroll
    for (int kk = 0; kk < 2; ++kk) {
      bf16x8 aq[2], bk[4];
      #pragma unroll
      for (int ti = 0; ti < 2; ++ti)
        aq[ti] = *(const bf16x8*)&Qs[(w * 32 + ti * 16 + l15) * 64 + kk * 32 + quad * 8];
      #pragma unroll
      for (int tj = 0; tj < 4; ++tj)
        bk[tj] = *(const bf16x8*)&Ks[(tj * 16 + l15) * 64 + kk * 32 + quad * 8];
      #pragma unroll
      for (int ti = 0; ti < 2; ++ti)
        #pragma unroll
        for (int tj = 0; tj < 4; ++tj)
          sacc[ti][tj] = __builtin_amdgcn_mfma_f32_16x16x32_bf16(aq[ti], bk[tj], sacc[ti][tj], 0, 0, 0);
    }

    // relu + causal mask, C-layout -> A-layout via LDS round trip
    const bool diag = (kt2 >= 2 * qt);  // only diagonal-crossing tiles need the mask
    #pragma unroll
    for (int ti = 0; ti < 2; ++ti)
      #pragma unroll
      for (int tj = 0; tj < 4; ++tj)
        #pragma unroll
        for (int r = 0; r < 4; ++r) {
          float v = fmaxf(sacc[ti][tj][r], 0.0f);
          if (diag) {
            int i_row = qt * 128 + w * 32 + ti * 16 + quad * 4 + r;
            int j_col = kt2 * 64 + tj * 16 + l15;
            if (j_col > i_row) v = 0.0f;
          }
          Ss[(w * 32 + ti * 16 + quad * 4 + r) * 72 + tj * 16 + l15] = (bf16_t)v;
        }
    __syncthreads();  // Ss ready

    // O += S . V : A = Ss[i][j], B = Vts[d][j]
    #pragma unroll
    for (int kk = 0; kk < 2; ++kk) {
      bf16x8 as_[2], bv[4];
      #pragma unroll
      for (int ti = 0; ti < 2; ++ti)
        as_[ti] = *(const bf16x8*)&Ss[(w * 32 + ti * 16 + l15) * 72 + kk * 32 + quad * 8];
      #pragma unroll
      for (int tj = 0; tj < 4; ++tj)
        bv[tj] = *(const bf16x8*)&Vts[(tj * 16 + l15) * 64 + kk * 32 + quad * 8];
      #pragma unroll
      for (int ti = 0; ti < 2; ++ti)
        #pragma unroll
        for (int tj = 0; tj < 4; ++tj)
          acc_o[ti][tj] = __builtin_amdgcn_mfma_f32_16x16x32_bf16(as_[ti], bv[tj], acc_o[ti][tj], 0, 0, 0);
    }
  }

  // epilogue: out[b][pos][h*64+d]
  #pragma unroll
  for (int ti = 0; ti < 2; ++ti)
    #pragma unroll
    for (int tj = 0; tj < 4; ++tj)
      #pragma unroll
      for (int r = 0; r < 4; ++r) {
        int pos = qt * 128 + w * 32 + ti * 16 + quad * 4 + r;
        int col = h * 64 + tj * 16 + l15;
        out[((size_t)b * 2048 + pos) * 1024 + col] = (bf16_t)acc_o[ti][tj][r];
      }
}

// ---------------------------------------------------------------------------
// launch
// ---------------------------------------------------------------------------
extern "C" void kernel_launch(void* const* d_in, const int* in_sizes, int n_in,
                              void* d_out, int out_size, void* d_ws, size_t ws_size,
                              hipStream_t stream) {
  (void)in_sizes; (void)n_in; (void)out_size; (void)ws_size;
  const float* x     = (const float*)d_in[0];
  const float* ln1_g = (const float*)d_in[1];
  const float* ln1_b = (const float*)d_in[2];
  const float* w_qkv = (const float*)d_in[3];
  const float* w_out = (const float*)d_in[4];
  const float* ln2_g = (const float*)d_in[5];
  const float* ln2_b = (const float*)d_in[6];
  float* out = (float*)d_out;

  char* ws = (char*)d_ws;
  // workspace layout (bytes), total ~75.5 MB
  bf16_t* xn     = (bf16_t*)(ws + 0);          //  8,388,608  [4096,1024]
  bf16_t* wqkvT  = (bf16_t*)(ws + 8388608);    //  6,291,456  [3072,1024]
  bf16_t* woutT  = (bf16_t*)(ws + 14680064);   //  2,097,152  [1024,1024]
  bf16_t* qb     = (bf16_t*)(ws + 16777216);   //  8,388,608  [2,16,2048,64]
  bf16_t* kb     = (bf16_t*)(ws + 25165824);   //  8,388,608
  bf16_t* vb     = (bf16_t*)(ws + 33554432);   //  8,388,608
  bf16_t* vTb    = (bf16_t*)(ws + 41943040);   //  8,388,608  [2,16,64,2048]
  bf16_t* ao     = (bf16_t*)(ws + 50331648);   //  8,388,608  [4096,1024]
  float*  z      = (float*)(ws + 58720256);    // 16,777,216  [4096,1024]

  ln1_kernel<<<4096, 256, 0, stream>>>(x, ln1_g, ln1_b, xn);
  wtrans_kernel<<<dim3(48, 16), 256, 0, stream>>>(w_qkv, wqkvT, 3072);
  wtrans_kernel<<<dim3(16, 16), 256, 0, stream>>>(w_out, woutT, 1024);
  gemm128_kernel<1><<<dim3(24, 32), 256, 0, stream>>>(xn, wqkvT, qb, kb, vb);
  vtrans_kernel<<<dim3(32, 32), 256, 0, stream>>>(vb, vTb);
  attn_kernel<<<dim3(16, 16, 2), 256, 0, stream>>>(qb, kb, vTb, ao);
  gemm128_kernel<0><<<dim3(8, 32), 256, 0, stream>>>(ao, woutT, z, nullptr, nullptr);
  ln2_kernel<<<4096, 256, 0, stream>>>(z, ln2_g, ln2_b, out);
}